// Round 4
// baseline (152.356 us; speedup 1.0000x reference)
//
#include <hip/hip_runtime.h>

// Chamfer loss: pred (2048,8,3) vs gt (2048,8,3) fp32. N=16384 pts/side.
// out = mean(min_m d) + mean(min_n d); 8-corner group-mean == global mean.
//
// R7: bidirectional MFMA, register-only hot loop (no LDS, no barriers,
// no atomics). Harness post-mortem: the 268MB ws re-poison (fillBuffer,
// 42us, 80% HBM peak) is INSIDE the timed region every round -> dur_us
// floor ~52us; R6's part kernel was ~40us (LDS-bound: 1.5 CU-LDS-cyc vs
// 1.2 CU-MFMA-cyc per MFMA, + 16 barriers/block at 2 blocks/CU).
//  - one S = pred.gt^T pass serves BOTH directions (1.05M MFMAs, half of
//    R6; same VALU: each S value feeds one row-merge and one col-merge).
//  - B-frags (wave's 256 y) resident in 64 VGPRs (R5-verified load);
//    A-frag global-load prefetched one x-tile ahead (L2-resident).
//  - row-flush per x-tile: DPP row_ror max (R6-verified, VALU pipe).
//    col-flush per wave at end: 2 shfl_xor (R5-verified).
//  - results -> plain coalesced stores into 64+64 partial-min slices (no
//    atomicMin); 128-block reduce kernel: min over 64 + sqrt + atomicAdd.
//  - bf16 3-way-split K-packing unchanged (absmax 0.0 in R5/R6):
//    acc = x.y - |x|^2/2 - |y|^2/2 = -d2/2 in one mfma_f32_16x16x32_bf16.

#define NPTS   16384
#define BLOCK  256            // 4 waves
#define XCH    256            // x-points per block (16 tiles)
#define NXC    (NPTS / XCH)   // 64
#define YCH    1024           // y-points per block
#define NYC    (NPTS / YCH)   // 16
#define YW     256            // y-points per wave (16 tiles in 64 VGPR)
#define ONEBF  0x3F80         // bf16 1.0

// ws: [0,1MB) Ppa | [1,2MB) Pgb | [2MB,10MB) part[2][64][NPTS] f32
#define WS_PGB  (1u << 20)
#define WS_PART (2u << 20)

typedef __attribute__((ext_vector_type(8))) short bf16x8;
typedef __attribute__((ext_vector_type(4))) float f32x4;

__device__ inline unsigned short f2bf(float f) {  // fp32 -> bf16 RNE
    unsigned int u = __float_as_uint(f);
    return (unsigned short)((u + 0x7FFFu + ((u >> 16) & 1u)) >> 16);
}
__device__ inline float bf2f(unsigned short h) {
    return __uint_as_float((unsigned int)h << 16);
}
__device__ inline void split3(float v, unsigned short* s) {
    unsigned short h = f2bf(v);  float r = v - bf2f(h);
    unsigned short m = f2bf(r);  r -= bf2f(m);
    s[0] = h; s[1] = m; s[2] = f2bf(r);
}

// K-slot map (identical order on A and B rows => lane->K bijection cancels):
//   s=c*3+d, c<6: cross combos (i,j)=(h,h)(h,m)(m,h)(h,l)(m,m)(l,h)
//   s=18..20: a=split3(-|p|^2/2), b=1 ; s=21..23: a=1, b=split3(-|p|^2/2)
//   s=24..31: 0   => S[r][c] = x.y - |x|^2/2 - |y|^2/2 = -d2/2
__device__ inline void build_rows(const float p[3], unsigned short* a,
                                  unsigned short* b) {
    const int CI[6] = {0, 0, 1, 0, 1, 2};
    const int CJ[6] = {0, 1, 0, 2, 1, 0};
    unsigned short xs[3][3], nn[3], t[3];
#pragma unroll
    for (int d = 0; d < 3; ++d) {
        split3(p[d], t);
        xs[0][d] = t[0]; xs[1][d] = t[1]; xs[2][d] = t[2];
    }
    split3(-0.5f * (p[0]*p[0] + p[1]*p[1] + p[2]*p[2]), nn);
#pragma unroll
    for (int c = 0; c < 6; ++c)
#pragma unroll
        for (int d = 0; d < 3; ++d) {
            a[c*3+d] = xs[CI[c]][d];
            b[c*3+d] = xs[CJ[c]][d];
        }
#pragma unroll
    for (int k = 0; k < 3; ++k) {
        a[18+k] = nn[k];  b[18+k] = ONEBF;
        a[21+k] = ONEBF;  b[21+k] = nn[k];
    }
#pragma unroll
    for (int k = 24; k < 32; ++k) { a[k] = 0; b[k] = 0; }
}

__device__ inline void store_row(unsigned short* dst, const unsigned short* s) {
    unsigned int w[16];
#pragma unroll
    for (int k = 0; k < 16; ++k)
        w[k] = (unsigned int)s[2*k] | ((unsigned int)s[2*k+1] << 16);
    uint4* d4 = reinterpret_cast<uint4*>(dst);
#pragma unroll
    for (int k = 0; k < 4; ++k)
        d4[k] = make_uint4(w[4*k], w[4*k+1], w[4*k+2], w[4*k+3]);
}

__global__ __launch_bounds__(256) void pack_points(
        const float* __restrict__ pred, const float* __restrict__ gt,
        unsigned short* __restrict__ Ppa, unsigned short* __restrict__ Pgb) {
    const int i = blockIdx.x * 256 + threadIdx.x;
    if (i >= NPTS) return;
    float p[3] = {pred[3*i], pred[3*i+1], pred[3*i+2]};
    float q[3] = {gt[3*i],   gt[3*i+1],   gt[3*i+2]};
    unsigned short ra[32], rb[32];
    build_rows(p, ra, rb);
    store_row(Ppa + (size_t)i * 32, ra);   // pred used as A (rows)
    build_rows(q, ra, rb);
    store_row(Pgb + (size_t)i * 32, rb);   // gt used as B (cols)
}

// DPP rotate-max within 16-lane rows (VALU pipe; verified in R6).
template <int CTRL>
__device__ inline float rormax(float v) {
    int t = __builtin_amdgcn_update_dpp(0, __float_as_int(v), CTRL, 0xF, 0xF,
                                        false);
    return fmaxf(v, __int_as_float(t));
}

__global__ __launch_bounds__(BLOCK, 4) void chamfer_bidi(
        const unsigned short* __restrict__ Ppa,
        const unsigned short* __restrict__ Pgb,
        float* __restrict__ part) {
    const int xb = blockIdx.x, yc = blockIdx.y;
    const int lane = threadIdx.x & 63, w = threadIdx.x >> 6;
    const int col = lane & 15, kg = lane >> 4;
    const int xbase = xb * XCH;
    const int ybase = yc * YCH + w * YW;

    // rowpart slice (yc*4+w): this wave's y-range partial of pred-mins.
    // colpart slice (64+xb): this block's x-range partial of gt-mins.
    // Slices are written at disjoint offsets by all contributing blocks.
    float* __restrict__ rowp = part + (size_t)(yc * 4 + w) * NPTS;
    float* __restrict__ colp = part + (size_t)(64 + xb) * NPTS;

    // wave-resident B fragments: 16 y-tiles x 4 VGPR = 64 VGPRs
    bf16x8 bfr[16];
#pragma unroll
    for (int yt = 0; yt < 16; ++yt)
        bfr[yt] = *reinterpret_cast<const bf16x8*>(
            Pgb + (size_t)(ybase + yt * 16 + col) * 32 + kg * 8);

    float cmax[16];
#pragma unroll
    for (int yt = 0; yt < 16; ++yt) cmax[yt] = -3.0e38f;

    const f32x4 z4 = {0.0f, 0.0f, 0.0f, 0.0f};

    // software-prefetch A-frag one x-tile ahead (named regs, no dyn index)
    bf16x8 afn = *reinterpret_cast<const bf16x8*>(
        Ppa + (size_t)(xbase + col) * 32 + kg * 8);

#pragma unroll 1
    for (int xt = 0; xt < 16; ++xt) {
        bf16x8 afc = afn;
        afn = *reinterpret_cast<const bf16x8*>(
            Ppa + (size_t)(xbase + (((xt + 1) & 15) * 16) + col) * 32 + kg * 8);

        f32x4 rmax = {-3.0e38f, -3.0e38f, -3.0e38f, -3.0e38f};
#pragma unroll
        for (int yt = 0; yt < 16; yt += 2) {
            f32x4 A = __builtin_amdgcn_mfma_f32_16x16x32_bf16(afc, bfr[yt],     z4, 0, 0, 0);
            f32x4 B = __builtin_amdgcn_mfma_f32_16x16x32_bf16(afc, bfr[yt + 1], z4, 0, 0, 0);
            // row-merge: 4 v_max3 per MFMA pair
            rmax.x = fmaxf(fmaxf(A.x, B.x), rmax.x);
            rmax.y = fmaxf(fmaxf(A.y, B.y), rmax.y);
            rmax.z = fmaxf(fmaxf(A.z, B.z), rmax.z);
            rmax.w = fmaxf(fmaxf(A.w, B.w), rmax.w);
            // col-merge: 2 v_max3 per MFMA
            float ta = fmaxf(fmaxf(A.x, A.y), A.z);
            cmax[yt]     = fmaxf(fmaxf(ta, A.w), cmax[yt]);
            float tb = fmaxf(fmaxf(B.x, B.y), B.z);
            cmax[yt + 1] = fmaxf(fmaxf(tb, B.w), cmax[yt + 1]);
        }

        // row flush: DPP ror-max over the 16 cols, store by col==0 lanes
#pragma unroll
        for (int i = 0; i < 4; ++i) {
            float v = rmax[i];
            v = rormax<0x121>(v);
            v = rormax<0x122>(v);
            v = rormax<0x124>(v);
            v = rormax<0x128>(v);
            if (col == 0)
                rowp[xbase + xt * 16 + kg * 4 + i] =
                    fmaxf(-2.0f * v, 0.0f);  // acc = -d2/2
        }
    }

    // col flush: reduce across the 4 row-groups (lane bits 4,5), store 16
    // contiguous y per (kg==0) group
#pragma unroll
    for (int yt = 0; yt < 16; ++yt) {
        float v = cmax[yt];
        v = fmaxf(v, __shfl_xor(v, 16, 64));
        v = fmaxf(v, __shfl_xor(v, 32, 64));
        if (kg == 0)
            colp[ybase + yt * 16 + col] = fmaxf(-2.0f * v, 0.0f);
    }
}

__global__ __launch_bounds__(256) void chamfer_reduce(
        const float* __restrict__ part, float* __restrict__ out) {
    const int gid = blockIdx.x * 256 + threadIdx.x;  // 128 blocks x 256
    const int side = gid >> 14, idx = gid & (NPTS - 1);
    const float* base = part + (size_t)side * 64 * NPTS + idx;
    float m = 3.0e38f;
#pragma unroll 8
    for (int c = 0; c < 64; ++c)
        m = fminf(m, base[(size_t)c * NPTS]);
    float s = sqrtf(m);
#pragma unroll
    for (int off = 32; off > 0; off >>= 1)
        s += __shfl_down(s, off, 64);
    if ((threadIdx.x & 63) == 0)
        atomicAdd(out, s * (1.0f / (float)NPTS));
}

extern "C" void kernel_launch(void* const* d_in, const int* in_sizes, int n_in,
                              void* d_out, int out_size, void* d_ws, size_t ws_size,
                              hipStream_t stream) {
    const float* pred = (const float*)d_in[0];
    const float* gt   = (const float*)d_in[1];
    float* out        = (float*)d_out;
    unsigned short* Ppa = (unsigned short*)d_ws;
    unsigned short* Pgb = (unsigned short*)((char*)d_ws + WS_PGB);
    float* part         = (float*)((char*)d_ws + WS_PART);

    hipMemsetAsync(d_out, 0, sizeof(float), stream);
    hipLaunchKernelGGL(pack_points, dim3(NPTS / 256), dim3(256), 0, stream,
                       pred, gt, Ppa, Pgb);
    hipLaunchKernelGGL(chamfer_bidi, dim3(NXC, NYC), dim3(BLOCK), 0, stream,
                       Ppa, Pgb, part);
    hipLaunchKernelGGL(chamfer_reduce, dim3(2 * NPTS / 256), dim3(256), 0, stream,
                       part, out);
}

// Round 5
// 140.823 us; speedup vs baseline: 1.0819x; 1.0819x over previous
//
#include <hip/hip_runtime.h>

// Chamfer loss: pred (2048,8,3) vs gt (2048,8,3) fp32. N=16384 pts/side.
// out = mean(min_m d) + mean(min_n d); 8-corner group-mean == global mean.
//
// R8: R7 post-mortem showed 62MB FETCH (A re-read stream missing L2: xb
// round-robins XCDs, so every XCD touches ALL packed data while 44MB of
// 16B-partial-line stores thrash its 4MB L2) -> latency-bound at 22%
// VALUBusy. Fixes, keeping the verified bf16-split bidi MFMA math:
//  - A-chunk (256 pts, 16KB) staged in LDS once per block; per-x-tile
//    A-frags via single ds_read_b128 (LDS pipe ~3x headroom vs MFMA).
//  - XCD swizzle: blockIdx.x = yc -> blocks sharing a B-chunk pin to
//    XCD yc%8; B/A stay L2-resident (fetch ~67MB -> ~10MB cold).
//  - row-min flushes accumulate in LDS (4KB); single end barrier, then
//    full-line coalesced stores (kills partial-line RMW write blowup).
//  - col-flush unchanged (already 64B-contiguous per instruction).
//  - grid (16,64) = 1024 blocks, 4/CU, 16 waves/CU; no atomics anywhere.
// Fixed costs each round: 268MB ws re-poison fill ~42us (harness, constant
// regardless of ws usage) + ~8us launch gaps. Only kernel time compresses.

#define NPTS   16384
#define BLOCK  256            // 4 waves
#define XCH    256            // x-points per block (16 tiles, 16KB packed)
#define NXC    (NPTS / XCH)   // 64
#define YW     256            // y-points per wave (16 tiles in 64 VGPR)
#define YCH    (4 * YW)       // 1024 y-points per block
#define NYC    (NPTS / YCH)   // 16
#define ONEBF  0x3F80         // bf16 1.0

// ws: [0,1MB) Ppa | [1,2MB) Pgb | [2MB,10MB) part[128][NPTS] f32
//   slices 0..63  = rowp (pred mins), slice id = yc*4+w  (y-range partial)
//   slices 64..127= colp (gt mins),   slice id = 64+xb   (x-range partial)
#define WS_PGB  (1u << 20)
#define WS_PART (2u << 20)

typedef __attribute__((ext_vector_type(8))) short bf16x8;
typedef __attribute__((ext_vector_type(4))) float f32x4;

__device__ inline unsigned short f2bf(float f) {  // fp32 -> bf16 RNE
    unsigned int u = __float_as_uint(f);
    return (unsigned short)((u + 0x7FFFu + ((u >> 16) & 1u)) >> 16);
}
__device__ inline float bf2f(unsigned short h) {
    return __uint_as_float((unsigned int)h << 16);
}
__device__ inline void split3(float v, unsigned short* s) {
    unsigned short h = f2bf(v);  float r = v - bf2f(h);
    unsigned short m = f2bf(r);  r -= bf2f(m);
    s[0] = h; s[1] = m; s[2] = f2bf(r);
}

// K-slot map (identical order on A and B rows => lane->K bijection cancels):
//   s=c*3+d, c<6: cross combos (i,j)=(h,h)(h,m)(m,h)(h,l)(m,m)(l,h)
//   s=18..20: a=split3(-|p|^2/2), b=1 ; s=21..23: a=1, b=split3(-|p|^2/2)
//   s=24..31: 0   => S[r][c] = x.y - |x|^2/2 - |y|^2/2 = -d2/2
__device__ inline void build_rows(const float p[3], unsigned short* a,
                                  unsigned short* b) {
    const int CI[6] = {0, 0, 1, 0, 1, 2};
    const int CJ[6] = {0, 1, 0, 2, 1, 0};
    unsigned short xs[3][3], nn[3], t[3];
#pragma unroll
    for (int d = 0; d < 3; ++d) {
        split3(p[d], t);
        xs[0][d] = t[0]; xs[1][d] = t[1]; xs[2][d] = t[2];
    }
    split3(-0.5f * (p[0]*p[0] + p[1]*p[1] + p[2]*p[2]), nn);
#pragma unroll
    for (int c = 0; c < 6; ++c)
#pragma unroll
        for (int d = 0; d < 3; ++d) {
            a[c*3+d] = xs[CI[c]][d];
            b[c*3+d] = xs[CJ[c]][d];
        }
#pragma unroll
    for (int k = 0; k < 3; ++k) {
        a[18+k] = nn[k];  b[18+k] = ONEBF;
        a[21+k] = ONEBF;  b[21+k] = nn[k];
    }
#pragma unroll
    for (int k = 24; k < 32; ++k) { a[k] = 0; b[k] = 0; }
}

__device__ inline void store_row(unsigned short* dst, const unsigned short* s) {
    unsigned int w[16];
#pragma unroll
    for (int k = 0; k < 16; ++k)
        w[k] = (unsigned int)s[2*k] | ((unsigned int)s[2*k+1] << 16);
    uint4* d4 = reinterpret_cast<uint4*>(dst);
#pragma unroll
    for (int k = 0; k < 4; ++k)
        d4[k] = make_uint4(w[4*k], w[4*k+1], w[4*k+2], w[4*k+3]);
}

__global__ __launch_bounds__(256) void pack_points(
        const float* __restrict__ pred, const float* __restrict__ gt,
        unsigned short* __restrict__ Ppa, unsigned short* __restrict__ Pgb) {
    const int i = blockIdx.x * 256 + threadIdx.x;
    if (i >= NPTS) return;
    float p[3] = {pred[3*i], pred[3*i+1], pred[3*i+2]};
    float q[3] = {gt[3*i],   gt[3*i+1],   gt[3*i+2]};
    unsigned short ra[32], rb[32];
    build_rows(p, ra, rb);
    store_row(Ppa + (size_t)i * 32, ra);   // pred used as A (rows)
    build_rows(q, ra, rb);
    store_row(Pgb + (size_t)i * 32, rb);   // gt used as B (cols)
}

// DPP rotate-max within 16-lane rows (VALU pipe; verified R6/R7).
template <int CTRL>
__device__ inline float rormax(float v) {
    int t = __builtin_amdgcn_update_dpp(0, __float_as_int(v), CTRL, 0xF, 0xF,
                                        false);
    return fmaxf(v, __int_as_float(t));
}

__global__ __launch_bounds__(BLOCK, 4) void chamfer_bidi(
        const unsigned short* __restrict__ Ppa,
        const unsigned short* __restrict__ Pgb,
        float* __restrict__ part) {
    const int yc = blockIdx.x;   // fastest-varying -> XCD = yc % 8 (B pin)
    const int xb = blockIdx.y;
    const int tid = threadIdx.x;
    const int lane = tid & 63, w = tid >> 6;
    const int col = lane & 15, kg = lane >> 4;
    const int xbase = xb * XCH;
    const int ybase = yc * YCH + w * YW;

    __shared__ __align__(16) unsigned short Ash[XCH * 32];  // 16 KB packed A
    __shared__ float rowacc[4][XCH];                        // 4 KB

    // stage A-chunk: 4 x 4KB fully-contiguous copies
    {
        const uint4* src = reinterpret_cast<const uint4*>(Ppa + (size_t)xbase * 32);
        uint4* dst = reinterpret_cast<uint4*>(Ash);
#pragma unroll
        for (int j = 0; j < 4; ++j)
            dst[j * 256 + tid] = src[j * 256 + tid];
    }

    // B-frags (wave's 256 y) resident in 64 VGPRs (one-time gather)
    bf16x8 bfr[16];
#pragma unroll
    for (int yt = 0; yt < 16; ++yt)
        bfr[yt] = *reinterpret_cast<const bf16x8*>(
            Pgb + (size_t)(ybase + yt * 16 + col) * 32 + kg * 8);

    float cmax[16];
#pragma unroll
    for (int yt = 0; yt < 16; ++yt) cmax[yt] = -3.0e38f;

    const f32x4 z4 = {0.0f, 0.0f, 0.0f, 0.0f};

    __syncthreads();  // Ash ready

    // A-frag prefetched one x-tile ahead, from LDS (ds_read_b128)
    bf16x8 afn = *reinterpret_cast<const bf16x8*>(Ash + col * 32 + kg * 8);

#pragma unroll 1
    for (int xt = 0; xt < 16; ++xt) {
        bf16x8 afc = afn;
        afn = *reinterpret_cast<const bf16x8*>(
            Ash + (((xt + 1) & 15) * 16 + col) * 32 + kg * 8);

        f32x4 rmax = {-3.0e38f, -3.0e38f, -3.0e38f, -3.0e38f};
#pragma unroll
        for (int yt = 0; yt < 16; yt += 2) {
            f32x4 A = __builtin_amdgcn_mfma_f32_16x16x32_bf16(afc, bfr[yt],     z4, 0, 0, 0);
            f32x4 B = __builtin_amdgcn_mfma_f32_16x16x32_bf16(afc, bfr[yt + 1], z4, 0, 0, 0);
            // row-merge: 4 v_max3 per MFMA pair
            rmax.x = fmaxf(fmaxf(A.x, B.x), rmax.x);
            rmax.y = fmaxf(fmaxf(A.y, B.y), rmax.y);
            rmax.z = fmaxf(fmaxf(A.z, B.z), rmax.z);
            rmax.w = fmaxf(fmaxf(A.w, B.w), rmax.w);
            // col-merge: 2 v_max3 per MFMA
            float ta = fmaxf(fmaxf(A.x, A.y), A.z);
            cmax[yt]     = fmaxf(fmaxf(ta, A.w), cmax[yt]);
            float tb = fmaxf(fmaxf(B.x, B.y), B.z);
            cmax[yt + 1] = fmaxf(fmaxf(tb, B.w), cmax[yt + 1]);
        }

        // row flush -> LDS accumulator (coalesced global store at the end)
#pragma unroll
        for (int i = 0; i < 4; ++i) {
            float v = rmax[i];
            v = rormax<0x121>(v);
            v = rormax<0x122>(v);
            v = rormax<0x124>(v);
            v = rormax<0x128>(v);
            if (col == 0)
                rowacc[w][xt * 16 + kg * 4 + i] = fmaxf(-2.0f * v, 0.0f);
        }
    }

    // col flush: reduce across the 4 row-groups; 64B-contiguous stores
#pragma unroll
    for (int yt = 0; yt < 16; ++yt) {
        float v = cmax[yt];
        v = fmaxf(v, __shfl_xor(v, 16, 64));
        v = fmaxf(v, __shfl_xor(v, 32, 64));
        if (kg == 0)
            part[(size_t)(64 + xb) * NPTS + ybase + yt * 16 + col] =
                fmaxf(-2.0f * v, 0.0f);
    }

    // row-min partials: full-line coalesced stores (1KB per slice-chunk)
    __syncthreads();  // rowacc complete across waves
#pragma unroll
    for (int ww = 0; ww < 4; ++ww)
        part[(size_t)(yc * 4 + ww) * NPTS + xbase + tid] = rowacc[ww][tid];
}

__global__ __launch_bounds__(256) void chamfer_reduce(
        const float* __restrict__ part, float* __restrict__ out) {
    const int gid = blockIdx.x * 256 + threadIdx.x;  // 128 blocks x 256
    const int side = gid >> 14, idx = gid & (NPTS - 1);
    const float* base = part + (size_t)side * 64 * NPTS + idx;
    float m = 3.0e38f;
#pragma unroll 8
    for (int c = 0; c < 64; ++c)
        m = fminf(m, base[(size_t)c * NPTS]);
    float s = sqrtf(m);
#pragma unroll
    for (int off = 32; off > 0; off >>= 1)
        s += __shfl_down(s, off, 64);
    if ((threadIdx.x & 63) == 0)
        atomicAdd(out, s * (1.0f / (float)NPTS));
}

extern "C" void kernel_launch(void* const* d_in, const int* in_sizes, int n_in,
                              void* d_out, int out_size, void* d_ws, size_t ws_size,
                              hipStream_t stream) {
    const float* pred = (const float*)d_in[0];
    const float* gt   = (const float*)d_in[1];
    float* out        = (float*)d_out;
    unsigned short* Ppa = (unsigned short*)d_ws;
    unsigned short* Pgb = (unsigned short*)((char*)d_ws + WS_PGB);
    float* part         = (float*)((char*)d_ws + WS_PART);

    hipMemsetAsync(d_out, 0, sizeof(float), stream);
    hipLaunchKernelGGL(pack_points, dim3(NPTS / 256), dim3(256), 0, stream,
                       pred, gt, Ppa, Pgb);
    hipLaunchKernelGGL(chamfer_bidi, dim3(NYC, NXC), dim3(BLOCK), 0, stream,
                       Ppa, Pgb, part);
    hipLaunchKernelGGL(chamfer_reduce, dim3(2 * NPTS / 256), dim3(256), 0, stream,
                       part, out);
}

// Round 6
// 116.291 us; speedup vs baseline: 1.3101x; 1.2110x over previous
//
#include <hip/hip_runtime.h>

// Chamfer loss: pred (2048,8,3) vs gt (2048,8,3) fp32. N=16384 pts/side.
// out = mean(min_m d) + mean(min_n d); 8-corner group-mean == global mean.
//
// R9: R7/R8 post-mortem = REGISTER SPILLING. VGPR_Count=64 vs ~100 live
// (bfr[16]=64 VGPRs), FETCH+WRITE carried ~70MB of scratch traffic
// (35 spilled regs x 4B x 64K threads x loop reloads), VALUBusy 24%.
// Fix: cut architectural demand below the 8-wave budget (64 VGPR):
//  - YW 256->128: bfr[8]=32 VGPRs, cmax[8]=8; live set ~64 -> no spill
//    under any waves-per-eu heuristic. Grid (32,64)=2048 blocks, 8/CU.
//  - everything else is the verified R8 structure: bf16 3-way-split
//    bidirectional MFMA (absmax 0.0 since R5), A-chunk in LDS, XCD pin
//    (XCD=yc%8, 128KB B per XCD L2), LDS rowacc + coalesced stores,
//    DPP ror-max row flush, shfl col flush, no atomics in hot path.
//  - partials: 128 row-slices (yc*4+w) + 64 col-slices (xb) = 12MB ws;
//    reduce kernel takes min over 128 resp. 64 slices + sqrt + atomicAdd.
// Fixed per round: 268MB ws re-poison fill ~42us + ~8us launch gaps.

#define NPTS   16384
#define BLOCK  256            // 4 waves
#define XCH    256            // x-points per block (16 tiles, 16KB packed)
#define NXC    (NPTS / XCH)   // 64
#define YW     128            // y-points per wave (8 tiles in 32 VGPR)
#define YCH    (4 * YW)       // 512 y-points per block
#define NYC    (NPTS / YCH)   // 32
#define ONEBF  0x3F80         // bf16 1.0

// ws: [0,1MB) Ppa | [1,2MB) Pgb | [2MB,14MB) part[192][NPTS] f32
//   slices 0..127  = row partials (pred mins), id = yc*4+w
//   slices 128..191= col partials (gt mins),   id = 128+xb
#define WS_PGB  (1u << 20)
#define WS_PART (2u << 20)
#define NROWSL  (NYC * 4)     // 128
#define NCOLSL  NXC           // 64

typedef __attribute__((ext_vector_type(8))) short bf16x8;
typedef __attribute__((ext_vector_type(4))) float f32x4;

__device__ inline unsigned short f2bf(float f) {  // fp32 -> bf16 RNE
    unsigned int u = __float_as_uint(f);
    return (unsigned short)((u + 0x7FFFu + ((u >> 16) & 1u)) >> 16);
}
__device__ inline float bf2f(unsigned short h) {
    return __uint_as_float((unsigned int)h << 16);
}
__device__ inline void split3(float v, unsigned short* s) {
    unsigned short h = f2bf(v);  float r = v - bf2f(h);
    unsigned short m = f2bf(r);  r -= bf2f(m);
    s[0] = h; s[1] = m; s[2] = f2bf(r);
}

// K-slot map (identical order on A and B rows => lane->K bijection cancels):
//   s=c*3+d, c<6: cross combos (i,j)=(h,h)(h,m)(m,h)(h,l)(m,m)(l,h)
//   s=18..20: a=split3(-|p|^2/2), b=1 ; s=21..23: a=1, b=split3(-|p|^2/2)
//   s=24..31: 0   => S[r][c] = x.y - |x|^2/2 - |y|^2/2 = -d2/2
__device__ inline void build_rows(const float p[3], unsigned short* a,
                                  unsigned short* b) {
    const int CI[6] = {0, 0, 1, 0, 1, 2};
    const int CJ[6] = {0, 1, 0, 2, 1, 0};
    unsigned short xs[3][3], nn[3], t[3];
#pragma unroll
    for (int d = 0; d < 3; ++d) {
        split3(p[d], t);
        xs[0][d] = t[0]; xs[1][d] = t[1]; xs[2][d] = t[2];
    }
    split3(-0.5f * (p[0]*p[0] + p[1]*p[1] + p[2]*p[2]), nn);
#pragma unroll
    for (int c = 0; c < 6; ++c)
#pragma unroll
        for (int d = 0; d < 3; ++d) {
            a[c*3+d] = xs[CI[c]][d];
            b[c*3+d] = xs[CJ[c]][d];
        }
#pragma unroll
    for (int k = 0; k < 3; ++k) {
        a[18+k] = nn[k];  b[18+k] = ONEBF;
        a[21+k] = ONEBF;  b[21+k] = nn[k];
    }
#pragma unroll
    for (int k = 24; k < 32; ++k) { a[k] = 0; b[k] = 0; }
}

__device__ inline void store_row(unsigned short* dst, const unsigned short* s) {
    unsigned int w[16];
#pragma unroll
    for (int k = 0; k < 16; ++k)
        w[k] = (unsigned int)s[2*k] | ((unsigned int)s[2*k+1] << 16);
    uint4* d4 = reinterpret_cast<uint4*>(dst);
#pragma unroll
    for (int k = 0; k < 4; ++k)
        d4[k] = make_uint4(w[4*k], w[4*k+1], w[4*k+2], w[4*k+3]);
}

__global__ __launch_bounds__(256) void pack_points(
        const float* __restrict__ pred, const float* __restrict__ gt,
        unsigned short* __restrict__ Ppa, unsigned short* __restrict__ Pgb) {
    const int i = blockIdx.x * 256 + threadIdx.x;
    if (i >= NPTS) return;
    float p[3] = {pred[3*i], pred[3*i+1], pred[3*i+2]};
    float q[3] = {gt[3*i],   gt[3*i+1],   gt[3*i+2]};
    unsigned short ra[32], rb[32];
    build_rows(p, ra, rb);
    store_row(Ppa + (size_t)i * 32, ra);   // pred used as A (rows)
    build_rows(q, ra, rb);
    store_row(Pgb + (size_t)i * 32, rb);   // gt used as B (cols)
}

// DPP rotate-max within 16-lane rows (VALU pipe; verified R6-R8).
template <int CTRL>
__device__ inline float rormax(float v) {
    int t = __builtin_amdgcn_update_dpp(0, __float_as_int(v), CTRL, 0xF, 0xF,
                                        false);
    return fmaxf(v, __int_as_float(t));
}

__global__ __launch_bounds__(BLOCK, 4) void chamfer_bidi(
        const unsigned short* __restrict__ Ppa,
        const unsigned short* __restrict__ Pgb,
        float* __restrict__ part) {
    const int yc = blockIdx.x;   // fastest-varying -> XCD = yc % 8 (B pin)
    const int xb = blockIdx.y;
    const int tid = threadIdx.x;
    const int lane = tid & 63, w = tid >> 6;
    const int col = lane & 15, kg = lane >> 4;
    const int xbase = xb * XCH;
    const int ybase = yc * YCH + w * YW;

    __shared__ __align__(16) unsigned short Ash[XCH * 32];  // 16 KB packed A
    __shared__ float rowacc[4][XCH];                        // 4 KB

    // stage A-chunk: 4 x 4KB fully-contiguous copies
    {
        const uint4* src = reinterpret_cast<const uint4*>(Ppa + (size_t)xbase * 32);
        uint4* dst = reinterpret_cast<uint4*>(Ash);
#pragma unroll
        for (int j = 0; j < 4; ++j)
            dst[j * 256 + tid] = src[j * 256 + tid];
    }

    // B-frags (wave's 128 y) resident in 32 VGPRs (one-time gather)
    bf16x8 bfr[8];
#pragma unroll
    for (int yt = 0; yt < 8; ++yt)
        bfr[yt] = *reinterpret_cast<const bf16x8*>(
            Pgb + (size_t)(ybase + yt * 16 + col) * 32 + kg * 8);

    float cmax[8];
#pragma unroll
    for (int yt = 0; yt < 8; ++yt) cmax[yt] = -3.0e38f;

    const f32x4 z4 = {0.0f, 0.0f, 0.0f, 0.0f};

    __syncthreads();  // Ash ready

    // A-frag prefetched one x-tile ahead, from LDS (ds_read_b128)
    bf16x8 afn = *reinterpret_cast<const bf16x8*>(Ash + col * 32 + kg * 8);

#pragma unroll 1
    for (int xt = 0; xt < 16; ++xt) {
        bf16x8 afc = afn;
        afn = *reinterpret_cast<const bf16x8*>(
            Ash + (((xt + 1) & 15) * 16 + col) * 32 + kg * 8);

        f32x4 rmax = {-3.0e38f, -3.0e38f, -3.0e38f, -3.0e38f};
#pragma unroll
        for (int yt = 0; yt < 8; yt += 2) {
            f32x4 A = __builtin_amdgcn_mfma_f32_16x16x32_bf16(afc, bfr[yt],     z4, 0, 0, 0);
            f32x4 B = __builtin_amdgcn_mfma_f32_16x16x32_bf16(afc, bfr[yt + 1], z4, 0, 0, 0);
            // row-merge: 4 v_max3 per MFMA pair
            rmax.x = fmaxf(fmaxf(A.x, B.x), rmax.x);
            rmax.y = fmaxf(fmaxf(A.y, B.y), rmax.y);
            rmax.z = fmaxf(fmaxf(A.z, B.z), rmax.z);
            rmax.w = fmaxf(fmaxf(A.w, B.w), rmax.w);
            // col-merge: 2 v_max3 per MFMA
            float ta = fmaxf(fmaxf(A.x, A.y), A.z);
            cmax[yt]     = fmaxf(fmaxf(ta, A.w), cmax[yt]);
            float tb = fmaxf(fmaxf(B.x, B.y), B.z);
            cmax[yt + 1] = fmaxf(fmaxf(tb, B.w), cmax[yt + 1]);
        }

        // row flush -> LDS accumulator (coalesced global store at the end)
#pragma unroll
        for (int i = 0; i < 4; ++i) {
            float v = rmax[i];
            v = rormax<0x121>(v);
            v = rormax<0x122>(v);
            v = rormax<0x124>(v);
            v = rormax<0x128>(v);
            if (col == 0)
                rowacc[w][xt * 16 + kg * 4 + i] = fmaxf(-2.0f * v, 0.0f);
        }
    }

    // col flush: reduce across the 4 row-groups; 64B-contiguous stores
#pragma unroll
    for (int yt = 0; yt < 8; ++yt) {
        float v = cmax[yt];
        v = fmaxf(v, __shfl_xor(v, 16, 64));
        v = fmaxf(v, __shfl_xor(v, 32, 64));
        if (kg == 0)
            part[(size_t)(NROWSL + xb) * NPTS + ybase + yt * 16 + col] =
                fmaxf(-2.0f * v, 0.0f);
    }

    // row-min partials: full-line coalesced stores (1KB per slice-chunk)
    __syncthreads();  // rowacc complete across waves
#pragma unroll
    for (int ww = 0; ww < 4; ++ww)
        part[(size_t)(yc * 4 + ww) * NPTS + xbase + tid] = rowacc[ww][tid];
}

__global__ __launch_bounds__(256) void chamfer_reduce(
        const float* __restrict__ part, float* __restrict__ out) {
    const int gid = blockIdx.x * 256 + threadIdx.x;  // 128 blocks x 256
    const int side = gid >> 14, idx = gid & (NPTS - 1);
    float m = 3.0e38f;
    if (side == 0) {
        const float* base = part + idx;
#pragma unroll 8
        for (int c = 0; c < NROWSL; ++c)
            m = fminf(m, base[(size_t)c * NPTS]);
    } else {
        const float* base = part + (size_t)NROWSL * NPTS + idx;
#pragma unroll 8
        for (int c = 0; c < NCOLSL; ++c)
            m = fminf(m, base[(size_t)c * NPTS]);
    }
    float s = sqrtf(m);
#pragma unroll
    for (int off = 32; off > 0; off >>= 1)
        s += __shfl_down(s, off, 64);
    if ((threadIdx.x & 63) == 0)
        atomicAdd(out, s * (1.0f / (float)NPTS));
}

extern "C" void kernel_launch(void* const* d_in, const int* in_sizes, int n_in,
                              void* d_out, int out_size, void* d_ws, size_t ws_size,
                              hipStream_t stream) {
    const float* pred = (const float*)d_in[0];
    const float* gt   = (const float*)d_in[1];
    float* out        = (float*)d_out;
    unsigned short* Ppa = (unsigned short*)d_ws;
    unsigned short* Pgb = (unsigned short*)((char*)d_ws + WS_PGB);
    float* part         = (float*)((char*)d_ws + WS_PART);

    hipMemsetAsync(d_out, 0, sizeof(float), stream);
    hipLaunchKernelGGL(pack_points, dim3(NPTS / 256), dim3(256), 0, stream,
                       pred, gt, Ppa, Pgb);
    hipLaunchKernelGGL(chamfer_bidi, dim3(NYC, NXC), dim3(BLOCK), 0, stream,
                       Ppa, Pgb, part);
    hipLaunchKernelGGL(chamfer_reduce, dim3(2 * NPTS / 256), dim3(256), 0, stream,
                       part, out);
}

// Round 7
// 96.000 us; speedup vs baseline: 1.5870x; 1.2114x over previous
//
#include <hip/hip_runtime.h>

// Chamfer loss: pred (2048,8,3) vs gt (2048,8,3) fp32. N=16384 pts/side.
// out = mean(min_m d) + mean(min_n d); 8-corner group-mean == global mean.
//
// R10: R9 confirmed direction (bidi left top-5, total 141->116) but
// accounting says bidi ~40us, still ~5x the ~7us VALU model. Residual
// theory: allocator still targets the 8-waves/EU 64-VGPR budget (R8
// evidence: VGPR_Count=64 while launch_bounds allowed 128 -> deliberate
// spill). Fixes:
//  - amdgpu_waves_per_eu(2,4): pins occupancy target to <=4 waves/EU
//    (VGPR budget >=128) so the backend has NO incentive to spill; true
//    demand ~66 (bfr[8]=32 + cmax[8] + afc 8 + rmax 4 + A/B 8 + addr).
//  - A-prefetch dropped (-8 VGPR): afc read from LDS at loop top; 4+
//    resident waves hide the ~120cyc LDS latency.
//  - rowacc: 4 waves' partials min-combined in-block -> 32 row slices
//    (was 128); partial traffic 12MB round trip -> 6MB.
//  - reduce kernel float4-vectorized (32 blocks); out zeroed in pack
//    (memset dispatch dropped).
// Unchanged verified core (absmax 0.0 since R5): bf16 3-way-split
// bidirectional MFMA (acc = -d2/2), A-chunk in LDS, XCD pin (yc%8),
// DPP ror-max row flush, shfl col flush, no atomics in hot path.
// Fixed per round: 268MB ws re-poison fill ~42us + reset/launch gaps.

#define NPTS   16384
#define BLOCK  256            // 4 waves
#define XCH    256            // x-points per block (16 tiles, 16KB packed)
#define NXC    (NPTS / XCH)   // 64
#define YW     128            // y-points per wave (8 tiles in 32 VGPR)
#define YCH    (4 * YW)       // 512 y-points per block
#define NYC    (NPTS / YCH)   // 32
#define ONEBF  0x3F80         // bf16 1.0

// ws: [0,1MB) Ppa | [1,2MB) Pgb | [2MB,8MB) part[96][NPTS] f32
//   slices 0..31  = row partials (pred mins), id = yc   (block-combined)
//   slices 32..95 = col partials (gt mins),   id = 32+xb
#define WS_PGB  (1u << 20)
#define WS_PART (2u << 20)
#define NROWSL  NYC           // 32
#define NCOLSL  NXC           // 64

typedef __attribute__((ext_vector_type(8))) short bf16x8;
typedef __attribute__((ext_vector_type(4))) float f32x4;

__device__ inline unsigned short f2bf(float f) {  // fp32 -> bf16 RNE
    unsigned int u = __float_as_uint(f);
    return (unsigned short)((u + 0x7FFFu + ((u >> 16) & 1u)) >> 16);
}
__device__ inline float bf2f(unsigned short h) {
    return __uint_as_float((unsigned int)h << 16);
}
__device__ inline void split3(float v, unsigned short* s) {
    unsigned short h = f2bf(v);  float r = v - bf2f(h);
    unsigned short m = f2bf(r);  r -= bf2f(m);
    s[0] = h; s[1] = m; s[2] = f2bf(r);
}

// K-slot map (identical order on A and B rows => lane->K bijection cancels):
//   s=c*3+d, c<6: cross combos (i,j)=(h,h)(h,m)(m,h)(h,l)(m,m)(l,h)
//   s=18..20: a=split3(-|p|^2/2), b=1 ; s=21..23: a=1, b=split3(-|p|^2/2)
//   s=24..31: 0   => S[r][c] = x.y - |x|^2/2 - |y|^2/2 = -d2/2
__device__ inline void build_rows(const float p[3], unsigned short* a,
                                  unsigned short* b) {
    const int CI[6] = {0, 0, 1, 0, 1, 2};
    const int CJ[6] = {0, 1, 0, 2, 1, 0};
    unsigned short xs[3][3], nn[3], t[3];
#pragma unroll
    for (int d = 0; d < 3; ++d) {
        split3(p[d], t);
        xs[0][d] = t[0]; xs[1][d] = t[1]; xs[2][d] = t[2];
    }
    split3(-0.5f * (p[0]*p[0] + p[1]*p[1] + p[2]*p[2]), nn);
#pragma unroll
    for (int c = 0; c < 6; ++c)
#pragma unroll
        for (int d = 0; d < 3; ++d) {
            a[c*3+d] = xs[CI[c]][d];
            b[c*3+d] = xs[CJ[c]][d];
        }
#pragma unroll
    for (int k = 0; k < 3; ++k) {
        a[18+k] = nn[k];  b[18+k] = ONEBF;
        a[21+k] = ONEBF;  b[21+k] = nn[k];
    }
#pragma unroll
    for (int k = 24; k < 32; ++k) { a[k] = 0; b[k] = 0; }
}

__device__ inline void store_row(unsigned short* dst, const unsigned short* s) {
    unsigned int w[16];
#pragma unroll
    for (int k = 0; k < 16; ++k)
        w[k] = (unsigned int)s[2*k] | ((unsigned int)s[2*k+1] << 16);
    uint4* d4 = reinterpret_cast<uint4*>(dst);
#pragma unroll
    for (int k = 0; k < 4; ++k)
        d4[k] = make_uint4(w[4*k], w[4*k+1], w[4*k+2], w[4*k+3]);
}

__global__ __launch_bounds__(256) void pack_points(
        const float* __restrict__ pred, const float* __restrict__ gt,
        unsigned short* __restrict__ Ppa, unsigned short* __restrict__ Pgb,
        float* __restrict__ out) {
    const int i = blockIdx.x * 256 + threadIdx.x;
    if (i == 0) out[0] = 0.0f;  // replaces the memset dispatch
    if (i >= NPTS) return;
    float p[3] = {pred[3*i], pred[3*i+1], pred[3*i+2]};
    float q[3] = {gt[3*i],   gt[3*i+1],   gt[3*i+2]};
    unsigned short ra[32], rb[32];
    build_rows(p, ra, rb);
    store_row(Ppa + (size_t)i * 32, ra);   // pred used as A (rows)
    build_rows(q, ra, rb);
    store_row(Pgb + (size_t)i * 32, rb);   // gt used as B (cols)
}

// DPP rotate-max within 16-lane rows (VALU pipe; verified R6-R9).
template <int CTRL>
__device__ inline float rormax(float v) {
    int t = __builtin_amdgcn_update_dpp(0, __float_as_int(v), CTRL, 0xF, 0xF,
                                        false);
    return fmaxf(v, __int_as_float(t));
}

__global__ __launch_bounds__(BLOCK)
__attribute__((amdgpu_waves_per_eu(2, 4)))  // VGPR budget >=128: forbid
void chamfer_bidi(                          // the 64-reg spill heuristic
        const unsigned short* __restrict__ Ppa,
        const unsigned short* __restrict__ Pgb,
        float* __restrict__ part) {
    const int yc = blockIdx.x;   // fastest-varying -> XCD = yc % 8 (B pin)
    const int xb = blockIdx.y;
    const int tid = threadIdx.x;
    const int lane = tid & 63, w = tid >> 6;
    const int col = lane & 15, kg = lane >> 4;
    const int xbase = xb * XCH;
    const int ybase = yc * YCH + w * YW;

    __shared__ __align__(16) unsigned short Ash[XCH * 32];  // 16 KB packed A
    __shared__ float rowacc[4][XCH];                        // 4 KB

    // stage A-chunk: 4 x 4KB fully-contiguous copies
    {
        const uint4* src = reinterpret_cast<const uint4*>(Ppa + (size_t)xbase * 32);
        uint4* dst = reinterpret_cast<uint4*>(Ash);
#pragma unroll
        for (int j = 0; j < 4; ++j)
            dst[j * 256 + tid] = src[j * 256 + tid];
    }

    // B-frags (wave's 128 y) resident in 32 VGPRs; each load instr covers
    // a contiguous 1KB ((col)*64 + kg*16 spans [0,1024)) -> coalesced
    bf16x8 bfr[8];
#pragma unroll
    for (int yt = 0; yt < 8; ++yt)
        bfr[yt] = *reinterpret_cast<const bf16x8*>(
            Pgb + (size_t)(ybase + yt * 16 + col) * 32 + kg * 8);

    float cmax[8];
#pragma unroll
    for (int yt = 0; yt < 8; ++yt) cmax[yt] = -3.0e38f;

    const f32x4 z4 = {0.0f, 0.0f, 0.0f, 0.0f};

    __syncthreads();  // Ash ready

#pragma unroll 1
    for (int xt = 0; xt < 16; ++xt) {
        // A-frag straight from LDS (no prefetch regs); contiguous-1KB
        // wave pattern -> conflict-free ds_read_b128
        bf16x8 afc = *reinterpret_cast<const bf16x8*>(
            Ash + (xt * 16 + col) * 32 + kg * 8);

        f32x4 rmax = {-3.0e38f, -3.0e38f, -3.0e38f, -3.0e38f};
#pragma unroll
        for (int yt = 0; yt < 8; yt += 2) {
            f32x4 A = __builtin_amdgcn_mfma_f32_16x16x32_bf16(afc, bfr[yt],     z4, 0, 0, 0);
            f32x4 B = __builtin_amdgcn_mfma_f32_16x16x32_bf16(afc, bfr[yt + 1], z4, 0, 0, 0);
            // row-merge: 4 v_max3 per MFMA pair
            rmax.x = fmaxf(fmaxf(A.x, B.x), rmax.x);
            rmax.y = fmaxf(fmaxf(A.y, B.y), rmax.y);
            rmax.z = fmaxf(fmaxf(A.z, B.z), rmax.z);
            rmax.w = fmaxf(fmaxf(A.w, B.w), rmax.w);
            // col-merge: 2 v_max3 per MFMA
            float ta = fmaxf(fmaxf(A.x, A.y), A.z);
            cmax[yt]     = fmaxf(fmaxf(ta, A.w), cmax[yt]);
            float tb = fmaxf(fmaxf(B.x, B.y), B.z);
            cmax[yt + 1] = fmaxf(fmaxf(tb, B.w), cmax[yt + 1]);
        }

        // row flush -> LDS accumulator (coalesced global store at the end)
#pragma unroll
        for (int i = 0; i < 4; ++i) {
            float v = rmax[i];
            v = rormax<0x121>(v);
            v = rormax<0x122>(v);
            v = rormax<0x124>(v);
            v = rormax<0x128>(v);
            if (col == 0)
                rowacc[w][xt * 16 + kg * 4 + i] = fmaxf(-2.0f * v, 0.0f);
        }
    }

    // col flush: reduce across the 4 row-groups; 64B-contiguous stores
#pragma unroll
    for (int yt = 0; yt < 8; ++yt) {
        float v = cmax[yt];
        v = fmaxf(v, __shfl_xor(v, 16, 64));
        v = fmaxf(v, __shfl_xor(v, 32, 64));
        if (kg == 0)
            part[(size_t)(NROWSL + xb) * NPTS + ybase + yt * 16 + col] =
                fmaxf(-2.0f * v, 0.0f);
    }

    // row-min partials: min-combine the 4 waves in-block -> ONE slice/yc,
    // full-line coalesced store
    __syncthreads();  // rowacc complete across waves
    float m = fminf(fminf(rowacc[0][tid], rowacc[1][tid]),
                    fminf(rowacc[2][tid], rowacc[3][tid]));
    part[(size_t)yc * NPTS + xbase + tid] = m;
}

__global__ __launch_bounds__(256) void chamfer_reduce(
        const float* __restrict__ part, float* __restrict__ out) {
    const int gid = blockIdx.x * 256 + threadIdx.x;  // 32 blocks x 256
    const int side = gid >> 12;                      // 4096 f32x4 per side
    const int idx4 = (gid & 4095) * 4;
    const int off  = side ? NROWSL : 0;
    const int cnt  = side ? NCOLSL : NROWSL;
    float4 m = make_float4(3.0e38f, 3.0e38f, 3.0e38f, 3.0e38f);
#pragma unroll 8
    for (int c = 0; c < cnt; ++c) {
        float4 v = *reinterpret_cast<const float4*>(
            part + (size_t)(off + c) * NPTS + idx4);
        m.x = fminf(m.x, v.x); m.y = fminf(m.y, v.y);
        m.z = fminf(m.z, v.z); m.w = fminf(m.w, v.w);
    }
    float s = sqrtf(m.x) + sqrtf(m.y) + sqrtf(m.z) + sqrtf(m.w);
#pragma unroll
    for (int o = 32; o > 0; o >>= 1)
        s += __shfl_down(s, o, 64);
    if ((threadIdx.x & 63) == 0)
        atomicAdd(out, s * (1.0f / (float)NPTS));
}

extern "C" void kernel_launch(void* const* d_in, const int* in_sizes, int n_in,
                              void* d_out, int out_size, void* d_ws, size_t ws_size,
                              hipStream_t stream) {
    const float* pred = (const float*)d_in[0];
    const float* gt   = (const float*)d_in[1];
    float* out        = (float*)d_out;
    unsigned short* Ppa = (unsigned short*)d_ws;
    unsigned short* Pgb = (unsigned short*)((char*)d_ws + WS_PGB);
    float* part         = (float*)((char*)d_ws + WS_PART);

    hipLaunchKernelGGL(pack_points, dim3(NPTS / 256), dim3(256), 0, stream,
                       pred, gt, Ppa, Pgb, out);
    hipLaunchKernelGGL(chamfer_bidi, dim3(NYC, NXC), dim3(BLOCK), 0, stream,
                       Ppa, Pgb, part);
    hipLaunchKernelGGL(chamfer_reduce, dim3(2 * NPTS / 1024), dim3(256), 0, stream,
                       part, out);
}